// Round 4
// baseline (4667.605 us; speedup 1.0000x reference)
//
#include <hip/hip_runtime.h>
#include <math.h>

#define B_ 1024
#define T_ 128
#define H_ 2048
#define C_ 10

typedef __bf16 bf16_t;
typedef __bf16 bf16x8 __attribute__((ext_vector_type(8)));
typedef __bf16 bf16x4 __attribute__((ext_vector_type(4)));
typedef float f32x4 __attribute__((ext_vector_type(4)));

// Static device storage: bf16 h ping-pong (8 MB), bf16 W_hh^T (8 MB),
// per-(t,bm) readiness counters (XCD-local handoff).
__device__ __align__(16) bf16_t g_hb[2][(size_t)B_ * H_];
__device__ __align__(16) bf16_t g_whhT[(size_t)H_ * H_];
__device__ int g_cnt[T_ * 8];   // [t][bm]; t=0 seeded to 32 by rnn_init

// AUX: cache policy. 0 = default; 1 = sc0 (force L1 miss -> read XCD L2).
template <int AUX>
__device__ __forceinline__ void gload16(const bf16_t* g, bf16_t* l) {
    __builtin_amdgcn_global_load_lds(
        (const __attribute__((address_space(1))) void*)g,
        (__attribute__((address_space(3))) void*)l, 16, 0, AUX);
}

// Counted-vmcnt barrier: retire oldest pipeline stage without draining.
template <int VM>
__device__ __forceinline__ void wait_vm_barrier() {
    asm volatile("s_waitcnt vmcnt(%0)\n\ts_barrier" :: "n"(VM) : "memory");
}

// One-time: W_hhT[n][k] = bf16(W_hh[k][n]) — B operand must be K-contiguous.
__global__ __launch_bounds__(256) void prep_whhT(const float* __restrict__ Whh) {
    __shared__ float tile[32][33];
    const int i  = threadIdx.x >> 3;
    const int j4 = (threadIdx.x & 7) * 4;
    const int r0 = blockIdx.y * 32;
    const int c0 = blockIdx.x * 32;
    f32x4 v = *(const f32x4*)(Whh + (size_t)(r0 + i) * H_ + c0 + j4);
    tile[i][j4 + 0] = v[0]; tile[i][j4 + 1] = v[1];
    tile[i][j4 + 2] = v[2]; tile[i][j4 + 3] = v[3];
    __syncthreads();
    bf16x4 o;
#pragma unroll
    for (int r = 0; r < 4; ++r) o[r] = (bf16_t)tile[j4 + r][i];
    *(bf16x4*)&g_whhT[(size_t)(c0 + i) * H_ + r0 + j4] = o;
}

// t = 0: h = tanh(x[:,0]*W_hx + b_h); also (re)initialize the counters.
__global__ __launch_bounds__(256) void rnn_init(const float* __restrict__ x,
                                                const float* __restrict__ Whx,
                                                const float* __restrict__ bh) {
    if (blockIdx.x == 0) {
        for (int i = threadIdx.x; i < T_ * 8; i += 256)
            g_cnt[i] = (i < 8) ? 32 : 0;   // g_cnt[0][*] = 32 (h0 ready)
    }
    const int gid = blockIdx.x * 256 + threadIdx.x;
    const int row = gid >> 9;
    const int col = (gid & 511) << 2;
    const float xv = x[(size_t)row * T_];
    f32x4 w = *(const f32x4*)&Whx[col];
    f32x4 b = *(const f32x4*)&bh[col];
    bf16x4 o;
#pragma unroll
    for (int j = 0; j < 4; ++j) o[j] = (bf16_t)tanhf(fmaf(xv, w[j], b[j]));
    *(bf16x4*)&g_hb[0][(size_t)row * H_ + col] = o;
}

// Persistent RNN, XCD-local sync (v1's proven rendezvous). v5 changes:
//  (1) B (W_hh^T) never touches LDS: fragments load global->VGPR into a
//      4-slot register rotation, prefetch distance 3, counted in the same
//      in-order vmcnt stream as the A stage loads. Cuts per-CU LDS traffic
//      2.34 -> 1.57 MB/step (floor 8.7 -> 5.8 us). B loads use default
//      caching: L1 serves the wave-pair duplication, L2 keeps zig-zag tail.
//  (2) 512 threads / 8 waves (wave tile 32x32): 2 waves per SIMD, so one
//      wave's MFMA issue covers another's ds/vmem waits (was 1 wave/SIMD,
//      every stall exposed, MfmaUtil 18%).
//  A ring: 6 slots x 16 KB = 96 KB; steady state waits vmcnt(14):
//  A lookahead 5 iters, B lookahead 3 iters (~1300 cyc > L3 latency).
__global__ __launch_bounds__(512, 1) void rnn_persist(const float* __restrict__ x,
                                                      const float* __restrict__ Whx,
                                                      const float* __restrict__ bh) {
    extern __shared__ __align__(16) bf16_t smem[];
    bf16_t* As = smem;                 // 6 slots x 8192 elems (16 KB each)

    const int tid  = threadIdx.x;
    const int lane = tid & 63;
    const int wave = tid >> 6;                       // 0..7
    const int li  = blockIdx.x;
    const int bm  = li & 7;                          // == XCD (blk%8 map)
    const int bn  = li >> 3;                         // 0..31

    const int wm = (wave >> 1) * 32;                 // row group (4)
    const int wn = (wave & 1) * 32;                  // col group (2)
    const int fr = lane & 15, fq = lane >> 4;

    // A staging: slot index s (0..1023) holds row s>>3, lds-chunk s&7;
    // global chunk = (s&7) ^ (row&7)  (8-row spread -> cheap frag reads).
    const int rA = tid >> 3;                         // 0..63
    const int cg = (tid & 7) ^ (rA & 7);
    const size_t aofsg = (size_t)(bm * 128 + rA) * H_ + cg * 8;

#define ISSUE_A(SLOT)                                                    \
    do {                                                                 \
        gload16<1>(gpa,           As + (SLOT) * 8192 + tid * 8);         \
        gload16<1>(gpa + 64 * H_, As + (SLOT) * 8192 + (tid + 512) * 8); \
        gpa += kstep;                                                    \
    } while (0)

    // B direct-to-reg: col = bn*64 + wn + j*16 + fr, k = chunk*64 + cc*32
    // + fq*8. 4 dwordx4 loads per chunk per wave; L1 broadcasts across the
    // 4 waves sharing wn.
    bf16x8 bB[4][2][2];                              // [slot][j][cc]
#define ISSUE_B(S)                                                       \
    do {                                                                 \
        bB[S][0][0] = *(const bf16x8*)(gpb);                             \
        bB[S][0][1] = *(const bf16x8*)(gpb + 32);                       \
        bB[S][1][0] = *(const bf16x8*)(gpb + 16 * H_);                  \
        bB[S][1][1] = *(const bf16x8*)(gpb + 16 * H_ + 32);             \
        gpb += kstep;                                                    \
    } while (0)

    // frag offsets (elems): row*64 + ((cc*4+fq) ^ (row&7))*8; row&7 == fr&7.
    int aoff[2][2];
#pragma unroll
    for (int i = 0; i < 2; ++i) {
        aoff[i][0] = (wm + i * 16 + fr) * 64 + ((0 + fq) ^ (fr & 7)) * 8;
        aoff[i][1] = (wm + i * 16 + fr) * 64 + ((4 + fq) ^ (fr & 7)) * 8;
    }

    f32x4 acc[2][2];

#define COMPUTE(SLOT, BS)                                                   \
    {                                                                       \
        _Pragma("unroll")                                                   \
        for (int cc = 0; cc < 2; ++cc) {                                    \
            bf16x8 af[2];                                                   \
            _Pragma("unroll")                                               \
            for (int i = 0; i < 2; ++i)                                     \
                af[i] = *(const bf16x8*)(As + (SLOT) * 8192 + aoff[i][cc]); \
            _Pragma("unroll")                                               \
            for (int i = 0; i < 2; ++i)                                     \
                _Pragma("unroll")                                           \
                for (int j = 0; j < 2; ++j)                                 \
                    acc[i][j] = __builtin_amdgcn_mfma_f32_16x16x32_bf16(    \
                        af[i], bB[BS][j][cc], acc[i][j], 0, 0, 0);          \
        }                                                                   \
    }

#define ITER(VM, BSI, ASI, CS, CB)                                          \
    do { wait_vm_barrier<VM>(); ISSUE_B(BSI); ISSUE_A(ASI);                 \
         COMPUTE(CS, CB); } while (0)
#define ITER_B(VM, BSI, CS, CB)                                             \
    do { wait_vm_barrier<VM>(); ISSUE_B(BSI); COMPUTE(CS, CB); } while (0)
#define ITER_N(VM, CS, CB)                                                  \
    do { wait_vm_barrier<VM>(); COMPUTE(CS, CB); } while (0)

    // epilogue constants (step-invariant)
    float wv[2], bv[2];
    int xbase[2];
#pragma unroll
    for (int j = 0; j < 2; ++j) {
        const int col = bn * 64 + wn + j * 16 + fr;
        wv[j] = Whx[col];
        bv[j] = bh[col];
    }
#pragma unroll
    for (int i = 0; i < 2; ++i)
        xbase[i] = (bm * 128 + wm + i * 16 + fq * 4) * T_;

    const bf16_t* const gb0w =
        g_whhT + (size_t)(bn * 64 + wn + fr) * H_ + fq * 8;

#pragma unroll 1
    for (int t = 1; t < T_; ++t) {
        const bf16_t* __restrict__ Abuf = g_hb[(t - 1) & 1];
        bf16_t* __restrict__ hn = g_hb[t & 1];
        // zig-zag: odd steps walk K from the top -- L2 still holds that tail
        const int koff  = (t & 1) ? (H_ - 64) : 0;
        const int kstep = (t & 1) ? -64 : 64;
        const bf16_t* gpa = Abuf + aofsg + koff;
        const bf16_t* gpb = gb0w + koff;

        // B is immutable: prefetch 3 chunks BEFORE the dependency wait.
        ISSUE_B(0); ISSUE_B(1); ISSUE_B(2);

        // wait until all 32 same-XCD writers of h-rows bm finished step t-1
        if (tid == 0) {
            while (__hip_atomic_load(&g_cnt[(t - 1) * 8 + bm], __ATOMIC_RELAXED,
                                     __HIP_MEMORY_SCOPE_AGENT) != 32)
                __builtin_amdgcn_s_sleep(2);
        }
        // control-only join (no data ordering needed: sc0 A-loads read L2,
        // writers drained before setting the flag). Raw barrier avoids the
        // compiler's conservative vmcnt(0) drain of the B prefetch.
        asm volatile("s_barrier" ::: "memory");

        ISSUE_A(0); ISSUE_A(1); ISSUE_A(2); ISSUE_A(3); ISSUE_A(4);

#pragma unroll
        for (int i = 0; i < 2; ++i)
#pragma unroll
            for (int j = 0; j < 2; ++j) acc[i][j] = (f32x4)(0.f);

        // 32 chunks. Stream/iter: B(k+3) [4 ops], A(k+5) [2 ops].
        // Steady wait vmcnt(14) retires A(k+1),B(k) -> A,B of chunk k ready.
        ITER(8 , 3, 5, 0, 0); ITER(12, 0, 0, 1, 1); ITER(16, 1, 1, 2, 2);
        ITER(14, 2, 2, 3, 3); ITER(14, 3, 3, 4, 0); ITER(14, 0, 4, 5, 1);
        ITER(14, 1, 5, 0, 2); ITER(14, 2, 0, 1, 3); ITER(14, 3, 1, 2, 0);
        ITER(14, 0, 2, 3, 1); ITER(14, 1, 3, 4, 2); ITER(14, 2, 4, 5, 3);
        ITER(14, 3, 5, 0, 0); ITER(14, 0, 0, 1, 1); ITER(14, 1, 1, 2, 2);
        ITER(14, 2, 2, 3, 3); ITER(14, 3, 3, 4, 0); ITER(14, 0, 4, 5, 1);
        ITER(14, 1, 5, 0, 2); ITER(14, 2, 0, 1, 3); ITER(14, 3, 1, 2, 0);
        ITER(14, 0, 2, 3, 1); ITER(14, 1, 3, 4, 2); ITER(14, 2, 4, 5, 3);
        ITER(14, 3, 5, 0, 0); ITER(14, 0, 0, 1, 1); ITER(14, 1, 1, 2, 2);
        ITER_B(14, 2, 3, 3);                       // it27: B30
        ITER_B(12, 3, 4, 0);                       // it28: B31
        ITER_N(10, 5, 1);                          // it29
        ITER_N(4 , 0, 2);                          // it30
        ITER_N(0 , 1, 3);                          // it31

        // epilogue: + x_t*W_hx + b_h, tanh, bf16 store
#pragma unroll
        for (int i = 0; i < 2; ++i) {
            const int row0 = bm * 128 + wm + i * 16 + fq * 4;
            float xv[4];
#pragma unroll
            for (int r = 0; r < 4; ++r) xv[r] = x[xbase[i] + r * T_ + t];
#pragma unroll
            for (int j = 0; j < 2; ++j) {
                const int col = bn * 64 + wn + j * 16 + fr;
#pragma unroll
                for (int r = 0; r < 4; ++r)
                    hn[(size_t)(row0 + r) * H_ + col] =
                        (bf16_t)tanhf(acc[i][j][r] + xv[r] * wv[j] + bv[j]);
            }
        }

        // publish: drain this wave's stores to L2, join waves, bump counter.
        asm volatile("s_waitcnt vmcnt(0)" ::: "memory");
        __syncthreads();
        if (tid == 0)
            __hip_atomic_fetch_add(&g_cnt[t * 8 + bm], 1, __ATOMIC_RELAXED,
                                   __HIP_MEMORY_SCOPE_AGENT);
    }
#undef ITER_N
#undef ITER_B
#undef ITER
#undef COMPUTE
#undef ISSUE_B
#undef ISSUE_A
}

// p = h_T @ W_ph + b_p : one wave per batch row, fp32 accumulate.
__global__ __launch_bounds__(64) void rnn_proj(const float* __restrict__ Wph,
                                               const float* __restrict__ bp,
                                               float* __restrict__ out, int sb) {
    const int b = blockIdx.x;
    const int l = threadIdx.x;
    const bf16_t* h = g_hb[sb] + (size_t)b * H_;
    float acc[C_];
#pragma unroll
    for (int c = 0; c < C_; ++c) acc[c] = 0.f;
    for (int k = l; k < H_; k += 64) {
        const float hv = (float)h[k];
#pragma unroll
        for (int c = 0; c < C_; ++c)
            acc[c] = fmaf(hv, Wph[k * C_ + c], acc[c]);
    }
#pragma unroll
    for (int off = 32; off > 0; off >>= 1)
#pragma unroll
        for (int c = 0; c < C_; ++c) acc[c] += __shfl_down(acc[c], off);
    if (l == 0) {
#pragma unroll
        for (int c = 0; c < C_; ++c) out[b * C_ + c] = acc[c] + bp[c];
    }
}

extern "C" void kernel_launch(void* const* d_in, const int* in_sizes, int n_in,
                              void* d_out, int out_size, void* d_ws, size_t ws_size,
                              hipStream_t stream) {
    const float* x   = (const float*)d_in[0];   // [1024,128]
    const float* Whx = (const float*)d_in[1];   // [1,2048]
    const float* Whh = (const float*)d_in[2];   // [2048,2048]
    const float* bh  = (const float*)d_in[3];   // [2048]
    const float* Wph = (const float*)d_in[4];   // [2048,10]
    const float* bp  = (const float*)d_in[5];   // [1,10]
    float* out = (float*)d_out;                 // [1024,10]

    static bool attr_set = false;
    if (!attr_set) {
        hipFuncSetAttribute((const void*)rnn_persist,
                            hipFuncAttributeMaxDynamicSharedMemorySize, 98304);
        attr_set = true;
    }

    prep_whhT<<<dim3(64, 64), 256, 0, stream>>>(Whh);
    rnn_init<<<(B_ * H_ / 4) / 256, 256, 0, stream>>>(x, Whx, bh);
    rnn_persist<<<256, 512, 98304, stream>>>(x, Whx, bh);
    rnn_proj<<<B_, 64, 0, stream>>>(Wph, bp, out, (T_ - 1) & 1);
}

// Round 5
// 3735.401 us; speedup vs baseline: 1.2496x; 1.2496x over previous
//
#include <hip/hip_runtime.h>
#include <math.h>

#define B_ 1024
#define T_ 128
#define H_ 2048
#define C_ 10

typedef __bf16 bf16_t;
typedef __bf16 bf16x8 __attribute__((ext_vector_type(8)));
typedef __bf16 bf16x4 __attribute__((ext_vector_type(4)));
typedef float f32x4 __attribute__((ext_vector_type(4)));

// Static device storage: bf16 h ping-pong (8 MB), bf16 W_hh^T (8 MB),
// per-(t,mt) readiness counters (XCD-local handoff; mt = 64-row M-tile).
__device__ __align__(16) bf16_t g_hb[2][(size_t)B_ * H_];
__device__ __align__(16) bf16_t g_whhT[(size_t)H_ * H_];
__device__ int g_cnt[T_ * 16];   // [t][mt]; t=0 seeded to 32 by rnn_init

// AUX: cache policy. 0 = default; 1 = sc0 (force L1 miss -> read XCD L2).
template <int AUX>
__device__ __forceinline__ void gload16(const bf16_t* g, bf16_t* l) {
    __builtin_amdgcn_global_load_lds(
        (const __attribute__((address_space(1))) void*)g,
        (__attribute__((address_space(3))) void*)l, 16, 0, AUX);
}

// Counted-vmcnt barrier: retire oldest pipeline stage without draining.
template <int VM>
__device__ __forceinline__ void wait_vm_barrier() {
    asm volatile("s_waitcnt vmcnt(%0)\n\ts_barrier" :: "n"(VM) : "memory");
}

// One-time: W_hhT[n][k] = bf16(W_hh[k][n]) — B operand must be K-contiguous.
__global__ __launch_bounds__(256) void prep_whhT(const float* __restrict__ Whh) {
    __shared__ float tile[32][33];
    const int i  = threadIdx.x >> 3;
    const int j4 = (threadIdx.x & 7) * 4;
    const int r0 = blockIdx.y * 32;
    const int c0 = blockIdx.x * 32;
    f32x4 v = *(const f32x4*)(Whh + (size_t)(r0 + i) * H_ + c0 + j4);
    tile[i][j4 + 0] = v[0]; tile[i][j4 + 1] = v[1];
    tile[i][j4 + 2] = v[2]; tile[i][j4 + 3] = v[3];
    __syncthreads();
    bf16x4 o;
#pragma unroll
    for (int r = 0; r < 4; ++r) o[r] = (bf16_t)tile[j4 + r][i];
    *(bf16x4*)&g_whhT[(size_t)(c0 + i) * H_ + r0 + j4] = o;
}

// t = 0: h = tanh(x[:,0]*W_hx + b_h); also (re)initialize the counters.
__global__ __launch_bounds__(256) void rnn_init(const float* __restrict__ x,
                                                const float* __restrict__ Whx,
                                                const float* __restrict__ bh) {
    if (blockIdx.x == 0) {
        for (int i = threadIdx.x; i < T_ * 16; i += 256)
            g_cnt[i] = (i < 16) ? 32 : 0;   // g_cnt[0][*] = 32 (h0 ready)
    }
    const int gid = blockIdx.x * 256 + threadIdx.x;
    const int row = gid >> 9;
    const int col = (gid & 511) << 2;
    const float xv = x[(size_t)row * T_];
    f32x4 w = *(const f32x4*)&Whx[col];
    f32x4 b = *(const f32x4*)&bh[col];
    bf16x4 o;
#pragma unroll
    for (int j = 0; j < 4; ++j) o[j] = (bf16_t)tanhf(fmaf(xv, w[j], b[j]));
    *(bf16x4*)&g_hb[0][(size_t)row * H_ + col] = o;
}

// Persistent RNN. v6 = v1's proven inner structure at 2x occupancy:
//  - 512 blocks of 64x64 tiles (was 256 of 128x64); 4 waves of 32x32.
//  - LDS 64 KB/block (4-stage AB ring) -> 2 blocks/CU, 2 waves/SIMD: while
//    one block sits in its per-step serial chain (drain, atomic, poll,
//    pipeline refill) or an L3 fill stall, the sibling block computes.
//    v1 ran 1 wave/SIMD (Occupancy 11.7%) with every stall exposed:
//    19.4 us/step vs ~8 us of bandwidth floors.
//  - Same XCD-local handoff: XCD = li&7 owns rows [XCD*128,+128) (two
//    64-row M-tiles); counter per (t, mt) counts its 32 writers, readers
//    poll then sc0-load A from the shared XCD L2. Same zig-zag K order.
//  - Uniform counted-vmcnt schedule: 4-op stages, 3 in flight, wait
//    vmcnt(8) every iter; no drain in the main loop.
//  - T5: s_setprio(1) around the MFMA cluster (sibling block provides the
//    wave role diversity that makes priority arbitration meaningful).
__global__ __launch_bounds__(256, 2) void rnn_persist(const float* __restrict__ x,
                                                      const float* __restrict__ Whx,
                                                      const float* __restrict__ bh) {
    extern __shared__ __align__(16) bf16_t smem[];
    bf16_t* As = smem;                 // 4 stages x 4096 elems (8 KB each)
    bf16_t* Bs = smem + 4 * 4096;      // 4 stages x 4096 elems (8 KB each)

    const int tid  = threadIdx.x;
    const int lane = tid & 63;
    const int wave = tid >> 6;
    const int li  = blockIdx.x;
    const int bm8 = li & 7;                          // XCD (blk%8 map)
    const int sub = li >> 3;                         // 0..63 within XCD
    const int mt  = bm8 * 2 + (sub & 1);             // M-tile: rows [mt*64,+64)
    const int bn  = sub >> 1;                        // 0..31 (64-col N-tile)

    const int wm = (wave & 1) * 32, wn = (wave >> 1) * 32;
    const int fr = lane & 15, fq = lane >> 4;

    // Staging: linear slot s holds row s>>3, lds-chunk s&7;
    // global chunk = (s&7) ^ (row&7)  (8-row spread -> 2-way frag reads).
    const int rA = tid >> 3;                         // 0..31 (+32 for op 2)
    const int cg = (tid & 7) ^ (rA & 7);
    const size_t aofsg = (size_t)(mt * 64 + rA) * H_ + cg * 8;
    const bf16_t* const gb0 = g_whhT + (size_t)(bn * 64 + rA) * H_ + cg * 8;

#define ISSUE_AB(SLOT)                                                   \
    do {                                                                 \
        gload16<1>(gpa,           As + (SLOT) * 4096 + tid * 8);         \
        gload16<1>(gpa + 32 * H_, As + (SLOT) * 4096 + (tid + 256) * 8); \
        gload16<0>(gpb,           Bs + (SLOT) * 4096 + tid * 8);         \
        gload16<0>(gpb + 32 * H_, Bs + (SLOT) * 4096 + (tid + 256) * 8); \
        gpa += kstep; gpb += kstep;                                      \
    } while (0)

    // frag offsets (elems): row*64 + ((cc*4+fq) ^ (row&7))*8; row&7 == fr&7.
    const int xr0 = (fq ^ (fr & 7)) * 8;
    const int xr1 = ((4 + fq) ^ (fr & 7)) * 8;
    int aoff[2][2], boff[2][2];
#pragma unroll
    for (int i = 0; i < 2; ++i) {
        aoff[i][0] = (wm + i * 16 + fr) * 64 + xr0;
        aoff[i][1] = (wm + i * 16 + fr) * 64 + xr1;
    }
#pragma unroll
    for (int j = 0; j < 2; ++j) {
        boff[j][0] = (wn + j * 16 + fr) * 64 + xr0;
        boff[j][1] = (wn + j * 16 + fr) * 64 + xr1;
    }

    f32x4 acc[2][2];

#define COMPUTE(SLOT)                                                       \
    {                                                                       \
        __builtin_amdgcn_s_setprio(1);                                      \
        _Pragma("unroll")                                                   \
        for (int cc = 0; cc < 2; ++cc) {                                    \
            bf16x8 af[2], bfv[2];                                           \
            _Pragma("unroll")                                               \
            for (int j = 0; j < 2; ++j)                                     \
                bfv[j] = *(const bf16x8*)(Bs + (SLOT) * 4096 + boff[j][cc]);\
            _Pragma("unroll")                                               \
            for (int i = 0; i < 2; ++i)                                     \
                af[i] = *(const bf16x8*)(As + (SLOT) * 4096 + aoff[i][cc]); \
            _Pragma("unroll")                                               \
            for (int i = 0; i < 2; ++i)                                     \
                _Pragma("unroll")                                           \
                for (int j = 0; j < 2; ++j)                                 \
                    acc[i][j] = __builtin_amdgcn_mfma_f32_16x16x32_bf16(    \
                        af[i], bfv[j], acc[i][j], 0, 0, 0);                 \
        }                                                                   \
        __builtin_amdgcn_s_setprio(0);                                      \
    }

#define ITER(ISS, CMP)                                                      \
    do { wait_vm_barrier<8>(); ISSUE_AB(ISS); COMPUTE(CMP); } while (0)

    // epilogue constants (step-invariant)
    float wv[2], bv[2];
    int xbase[2];
#pragma unroll
    for (int j = 0; j < 2; ++j) {
        const int col = bn * 64 + wn + j * 16 + fr;
        wv[j] = Whx[col];
        bv[j] = bh[col];
    }
#pragma unroll
    for (int i = 0; i < 2; ++i)
        xbase[i] = (mt * 64 + wm + i * 16 + fq * 4) * T_;

#pragma unroll 1
    for (int t = 1; t < T_; ++t) {
        const bf16_t* __restrict__ Abuf = g_hb[(t - 1) & 1];
        bf16_t* __restrict__ hn = g_hb[t & 1];
        // zig-zag: odd steps walk K from the top -- L2 still holds that tail
        const int koff  = (t & 1) ? (H_ - 64) : 0;
        const int kstep = (t & 1) ? -64 : 64;
        const bf16_t* gpa = Abuf + aofsg + koff;
        const bf16_t* gpb = gb0 + koff;

        // wait until all 32 writers of h-rows [mt*64,+64) finished step t-1
        if (tid == 0) {
            while (__hip_atomic_load(&g_cnt[(t - 1) * 16 + mt], __ATOMIC_RELAXED,
                                     __HIP_MEMORY_SCOPE_AGENT) != 32)
                __builtin_amdgcn_s_sleep(2);
        }
        __syncthreads();          // no agent fence: sc0 A-loads read fresh L2

        // prologue: chunks 0..2 (12 ops). sched_barrier pins group order so
        // the in-order vmcnt retirement counts stay exact.
        ISSUE_AB(0);
        __builtin_amdgcn_sched_barrier(0);
        ISSUE_AB(1);
        __builtin_amdgcn_sched_barrier(0);
        ISSUE_AB(2);

#pragma unroll
        for (int i = 0; i < 2; ++i)
#pragma unroll
            for (int j = 0; j < 2; ++j) acc[i][j] = (f32x4)(0.f);

        // 32 chunks, 4-slot ring, 3 stages in flight, uniform vmcnt(8).
#pragma unroll
        for (int g = 0; g < 7; ++g) {                 // iters 0..27
            ITER(3, 0); ITER(0, 1); ITER(1, 2); ITER(2, 3);
        }
        ITER(3, 0);                                   // iter 28 (issues 31)
        wait_vm_barrier<8>(); COMPUTE(1);             // iter 29
        wait_vm_barrier<4>(); COMPUTE(2);             // iter 30
        wait_vm_barrier<0>(); COMPUTE(3);             // iter 31

        // epilogue: + x_t*W_hx + b_h, tanh, bf16 store
#pragma unroll
        for (int i = 0; i < 2; ++i) {
            const int row0 = mt * 64 + wm + i * 16 + fq * 4;
            float xv[4];
#pragma unroll
            for (int r = 0; r < 4; ++r) xv[r] = x[xbase[i] + r * T_ + t];
#pragma unroll
            for (int j = 0; j < 2; ++j) {
                const int col = bn * 64 + wn + j * 16 + fr;
#pragma unroll
                for (int r = 0; r < 4; ++r)
                    hn[(size_t)(row0 + r) * H_ + col] =
                        (bf16_t)tanhf(acc[i][j][r] + xv[r] * wv[j] + bv[j]);
            }
        }

        // publish: drain this wave's stores to L2, join waves, bump counter.
        asm volatile("s_waitcnt vmcnt(0)" ::: "memory");
        __syncthreads();
        if (tid == 0)
            __hip_atomic_fetch_add(&g_cnt[t * 16 + mt], 1, __ATOMIC_RELAXED,
                                   __HIP_MEMORY_SCOPE_AGENT);
    }
#undef ITER
#undef COMPUTE
#undef ISSUE_AB
}

// p = h_T @ W_ph + b_p : one wave per batch row, fp32 accumulate.
__global__ __launch_bounds__(64) void rnn_proj(const float* __restrict__ Wph,
                                               const float* __restrict__ bp,
                                               float* __restrict__ out, int sb) {
    const int b = blockIdx.x;
    const int l = threadIdx.x;
    const bf16_t* h = g_hb[sb] + (size_t)b * H_;
    float acc[C_];
#pragma unroll
    for (int c = 0; c < C_; ++c) acc[c] = 0.f;
    for (int k = l; k < H_; k += 64) {
        const float hv = (float)h[k];
#pragma unroll
        for (int c = 0; c < C_; ++c)
            acc[c] = fmaf(hv, Wph[k * C_ + c], acc[c]);
    }
#pragma unroll
    for (int off = 32; off > 0; off >>= 1)
#pragma unroll
        for (int c = 0; c < C_; ++c) acc[c] += __shfl_down(acc[c], off);
    if (l == 0) {
#pragma unroll
        for (int c = 0; c < C_; ++c) out[b * C_ + c] = acc[c] + bp[c];
    }
}

extern "C" void kernel_launch(void* const* d_in, const int* in_sizes, int n_in,
                              void* d_out, int out_size, void* d_ws, size_t ws_size,
                              hipStream_t stream) {
    const float* x   = (const float*)d_in[0];   // [1024,128]
    const float* Whx = (const float*)d_in[1];   // [1,2048]
    const float* Whh = (const float*)d_in[2];   // [2048,2048]
    const float* bh  = (const float*)d_in[3];   // [2048]
    const float* Wph = (const float*)d_in[4];   // [2048,10]
    const float* bp  = (const float*)d_in[5];   // [1,10]
    float* out = (float*)d_out;                 // [1024,10]

    static bool attr_set = false;
    if (!attr_set) {
        hipFuncSetAttribute((const void*)rnn_persist,
                            hipFuncAttributeMaxDynamicSharedMemorySize, 65536);
        attr_set = true;
    }

    prep_whhT<<<dim3(64, 64), 256, 0, stream>>>(Whh);
    rnn_init<<<(B_ * H_ / 4) / 256, 256, 0, stream>>>(x, Whx, bh);
    rnn_persist<<<512, 256, 65536, stream>>>(x, Whx, bh);
    rnn_proj<<<B_, 64, 0, stream>>>(Wph, bp, out, (T_ - 1) & 1);
}

// Round 6
// 2192.245 us; speedup vs baseline: 2.1291x; 1.7039x over previous
//
#include <hip/hip_runtime.h>
#include <math.h>

#define B_ 1024
#define T_ 128
#define H_ 2048
#define C_ 10

typedef __bf16 bf16_t;
typedef __bf16 bf16x8 __attribute__((ext_vector_type(8)));
typedef __bf16 bf16x4 __attribute__((ext_vector_type(4)));
typedef float f32x4 __attribute__((ext_vector_type(4)));

// Static device storage: bf16 h ping-pong (8 MB), bf16 W_hh^T (8 MB),
// per-(t,bm) readiness counters (XCD-local handoff).
__device__ __align__(16) bf16_t g_hb[2][(size_t)B_ * H_];
__device__ __align__(16) bf16_t g_whhT[(size_t)H_ * H_];
__device__ int g_cnt[T_ * 8];   // [t][bm]; t=0 seeded to 32 by rnn_init

// AUX: cache policy. 0 = default; 1 = sc0 (force L1 miss -> read XCD L2).
template <int AUX>
__device__ __forceinline__ void gload16(const bf16_t* g, bf16_t* l) {
    __builtin_amdgcn_global_load_lds(
        (const __attribute__((address_space(1))) void*)g,
        (__attribute__((address_space(3))) void*)l, 16, 0, AUX);
}

// Counted-vmcnt barrier: retire oldest pipeline stage without draining.
template <int VM>
__device__ __forceinline__ void wait_vm_barrier() {
    asm volatile("s_waitcnt vmcnt(%0)\n\ts_barrier" :: "n"(VM) : "memory");
}

// One-time: W_hhT[n][k] = bf16(W_hh[k][n]) — B operand must be K-contiguous.
__global__ __launch_bounds__(256) void prep_whhT(const float* __restrict__ Whh) {
    __shared__ float tile[32][33];
    const int i  = threadIdx.x >> 3;
    const int j4 = (threadIdx.x & 7) * 4;
    const int r0 = blockIdx.y * 32;
    const int c0 = blockIdx.x * 32;
    f32x4 v = *(const f32x4*)(Whh + (size_t)(r0 + i) * H_ + c0 + j4);
    tile[i][j4 + 0] = v[0]; tile[i][j4 + 1] = v[1];
    tile[i][j4 + 2] = v[2]; tile[i][j4 + 3] = v[3];
    __syncthreads();
    bf16x4 o;
#pragma unroll
    for (int r = 0; r < 4; ++r) o[r] = (bf16_t)tile[j4 + r][i];
    *(bf16x4*)&g_whhT[(size_t)(c0 + i) * H_ + r0 + j4] = o;
}

// t = 0: h = tanh(x[:,0]*W_hx + b_h); also (re)initialize the counters.
__global__ __launch_bounds__(256) void rnn_init(const float* __restrict__ x,
                                                const float* __restrict__ Whx,
                                                const float* __restrict__ bh) {
    if (blockIdx.x == 0) {
        for (int i = threadIdx.x; i < T_ * 8; i += 256)
            g_cnt[i] = (i < 8) ? 32 : 0;   // g_cnt[0][*] = 32 (h0 ready)
    }
    const int gid = blockIdx.x * 256 + threadIdx.x;
    const int row = gid >> 9;
    const int col = (gid & 511) << 2;
    const float xv = x[(size_t)row * T_];
    f32x4 w = *(const f32x4*)&Whx[col];
    f32x4 b = *(const f32x4*)&bh[col];
    bf16x4 o;
#pragma unroll
    for (int j = 0; j < 4; ++j) o[j] = (bf16_t)tanhf(fmaf(xv, w[j], b[j]));
    *(bf16x4*)&g_hb[0][(size_t)row * H_ + col] = o;
}

// Persistent RNN. v7 = v1's proven structure (same 256 blocks, same 128x64
// tile, same 147 KB 6-slot ring, same staging order/swizzle, same XCD-local
// rendezvous, same zig-zag) with ONE change: 512 threads = 8 waves arranged
// 2M x 2N x 2K-parity. Each wave is exactly a v1 wave (64x32 tile,
// acc[4][2], 16 MFMA + 12 ds_read per chunk) but computes only chunks of
// its K-parity (16 of 32). Two waves per SIMD -> one wave's MFMA covers the
// other's ds_read/vm-wait bubbles. Traffic per CU per step is BIT-IDENTICAL
// to v1 (MFMA 2048, LDS frag reads 1.57 MB, staged 768 KB); the only
// additions are a padded LDS K-reduce (aliased into dead ring slots) and
// one extra barrier. In-order stream per thread: B0..B3 | A0A0..A3A3 |
// per-iter [A,A,B]x2 for chunks p+4,p+5; steady wait vmcnt(6) retires one
// chunk pair (12 loads/thread in flight = 98 KB/CU, ~v1 depth).
__global__ __launch_bounds__(512, 1) void rnn_persist(const float* __restrict__ x,
                                                      const float* __restrict__ Whx,
                                                      const float* __restrict__ bh) {
    extern __shared__ __align__(16) bf16_t smem[];
    bf16_t* As = smem;                 // 6 slots x 8192 elems (16 KB each)
    bf16_t* Bs = smem + 6 * 8192;      // 6 slots x 4096 elems (8 KB each)
    // K-reduce scratch: aliases As slots 2..4 (dead when the reduce runs).
    float* red = (float*)(As + 2 * 8192);   // 8 waves x 1056 f32 (pad 33)

    const int tid  = threadIdx.x;
    const int lane = tid & 63;
    const int wave = tid >> 6;                       // 0..7
    const int li  = blockIdx.x;
    const int bm  = li & 7;                          // == XCD (blk%8 map)
    const int bn  = li >> 3;                         // 0..31

    const int wm = (wave & 1) * 64;                  // M band (64 rows)
    const int wn = ((wave >> 1) & 1) * 32;           // N band (32 cols)
    const int kh = wave >> 2;                        // K parity (chunk&1)
    const int fr = lane & 15, fq = lane >> 4;

    // Staging: linear slot s holds row s>>3, lds-chunk s&7;
    // global chunk = (s&7) ^ (row&7)  (8-row spread -> 2-way frag reads).
    // 512 threads: A = 2 loads/thread (rows 0..63, 64..127), B = 1.
    const int rA = tid >> 3;                         // 0..63
    const int cg = (tid & 7) ^ (rA & 7);
    const size_t aofsg = (size_t)(bm * 128 + rA) * H_ + cg * 8;
    const bf16_t* const gb0 = g_whhT + (size_t)(bn * 64 + rA) * H_ + cg * 8;

#define ISSUE_A(SLOT)                                                    \
    do {                                                                 \
        gload16<1>(gpa,           As + (SLOT) * 8192 + tid * 8);         \
        gload16<1>(gpa + 64 * H_, As + (SLOT) * 8192 + (tid + 512) * 8); \
        gpa += kstep;                                                    \
    } while (0)
#define ISSUE_B(SLOT)                                                    \
    do {                                                                 \
        gload16<0>(gpb, Bs + (SLOT) * 4096 + tid * 8);                   \
        gpb += kstep;                                                    \
    } while (0)

    // frag offsets (elems): row*64 + ((cc*4+fq) ^ (row&7))*8; row&7 == fr&7.
    const int xr0 = (fq ^ (fr & 7)) * 8;
    const int xr1 = ((4 + fq) ^ (fr & 7)) * 8;
    int aoff[4][2], boff[2][2];
#pragma unroll
    for (int i = 0; i < 4; ++i) {
        aoff[i][0] = (wm + i * 16 + fr) * 64 + xr0;
        aoff[i][1] = (wm + i * 16 + fr) * 64 + xr1;
    }
#pragma unroll
    for (int j = 0; j < 2; ++j) {
        boff[j][0] = (wn + j * 16 + fr) * 64 + xr0;
        boff[j][1] = (wn + j * 16 + fr) * 64 + xr1;
    }

    f32x4 acc[4][2];

#define COMPUTE(SLOT)                                                       \
    {                                                                       \
        _Pragma("unroll")                                                   \
        for (int cc = 0; cc < 2; ++cc) {                                    \
            bf16x8 af[4], bfv[2];                                           \
            _Pragma("unroll")                                               \
            for (int j = 0; j < 2; ++j)                                     \
                bfv[j] = *(const bf16x8*)(Bs + (SLOT) * 4096 + boff[j][cc]);\
            _Pragma("unroll")                                               \
            for (int i = 0; i < 4; ++i)                                     \
                af[i] = *(const bf16x8*)(As + (SLOT) * 8192 + aoff[i][cc]); \
            _Pragma("unroll")                                               \
            for (int i = 0; i < 4; ++i)                                     \
                _Pragma("unroll")                                           \
                for (int j = 0; j < 2; ++j)                                 \
                    acc[i][j] = __builtin_amdgcn_mfma_f32_16x16x32_bf16(    \
                        af[i], bfv[j], acc[i][j], 0, 0, 0);                 \
        }                                                                   \
    }

    // kh selects which parity's slot this wave computes (wave-uniform).
#define CMP(CE, CO)                                                         \
    do { if (kh == 0) COMPUTE(CE) else COMPUTE(CO) } while (0)

#define ITER(VM, IS1, IS2, CE, CO)                                          \
    do { wait_vm_barrier<VM>(); ISSUE_A(IS1); ISSUE_B(IS1);                 \
         ISSUE_A(IS2); ISSUE_B(IS2); CMP(CE, CO); } while (0)

    // epilogue constants (step-invariant)
    float wv[2], bv[2];
#pragma unroll
    for (int j = 0; j < 2; ++j) {
        const int col = bn * 64 + wn + j * 16 + fr;
        wv[j] = Whx[col];
        bv[j] = bh[col];
    }

#pragma unroll 1
    for (int t = 1; t < T_; ++t) {
        const bf16_t* __restrict__ Abuf = g_hb[(t - 1) & 1];
        bf16_t* __restrict__ hn = g_hb[t & 1];
        // zig-zag: odd steps walk K from the top -- L2 still holds that tail
        const int koff  = (t & 1) ? (H_ - 64) : 0;
        const int kstep = (t & 1) ? -64 : 64;
        const bf16_t* gpa = Abuf + aofsg + koff;
        const bf16_t* gpb = gb0 + koff;

        // B is immutable: stage positions 0..3 BEFORE the dependency wait.
        ISSUE_B(0); ISSUE_B(1); ISSUE_B(2); ISSUE_B(3);

        // wait until all 32 same-XCD writers of h-rows bm finished step t-1
        if (tid == 0) {
            while (__hip_atomic_load(&g_cnt[(t - 1) * 8 + bm], __ATOMIC_RELAXED,
                                     __HIP_MEMORY_SCOPE_AGENT) != 32)
                __builtin_amdgcn_s_sleep(2);
        }
        // raw barrier: keeps the B prefetch alive (no vmcnt(0) drain);
        // sc0 A-loads read the fresh XCD L2 (validated pattern, v6 passed).
        asm volatile("s_barrier" ::: "memory");

        ISSUE_A(0); ISSUE_A(1); ISSUE_A(2); ISSUE_A(3);

#pragma unroll
        for (int i = 0; i < 4; ++i)
#pragma unroll
            for (int j = 0; j < 2; ++j) acc[i][j] = (f32x4)(0.f);

        // 16 super-iters, 2 chunks each; 6-slot ring; steady vmcnt(6).
        ITER(4, 4, 5, 0, 1);                          // u0
        ITER(6, 0, 1, 2, 3);  ITER(6, 2, 3, 4, 5);    // u1,u2
        ITER(6, 4, 5, 0, 1);  ITER(6, 0, 1, 2, 3);    // u3,u4
        ITER(6, 2, 3, 4, 5);  ITER(6, 4, 5, 0, 1);    // u5,u6
        ITER(6, 0, 1, 2, 3);  ITER(6, 2, 3, 4, 5);    // u7,u8
        ITER(6, 4, 5, 0, 1);  ITER(6, 0, 1, 2, 3);    // u9,u10
        ITER(6, 2, 3, 4, 5);  ITER(6, 4, 5, 0, 1);    // u11,u12
        ITER(6, 0, 1, 2, 3);                          // u13 (issues p30,31)
        wait_vm_barrier<6>(); CMP(4, 5);              // u14
        wait_vm_barrier<0>(); CMP(0, 1);              // u15

        // ---- cross-wave K-parity reduce (partner = wave^4).
        // Write NON-kept M-half (32x32 f32, pad 33) to own region; read
        // partner's region (their non-kept == our kept) and add.
        {
            float* wr = red + wave * 1056;
            if (kh == 0) {
#pragma unroll
                for (int ii = 0; ii < 2; ++ii)
#pragma unroll
                    for (int j = 0; j < 2; ++j)
#pragma unroll
                        for (int r = 0; r < 4; ++r)
                            wr[(ii * 16 + fq * 4 + r) * 33 + j * 16 + fr] =
                                acc[2 + ii][j][r];
            } else {
#pragma unroll
                for (int ii = 0; ii < 2; ++ii)
#pragma unroll
                    for (int j = 0; j < 2; ++j)
#pragma unroll
                        for (int r = 0; r < 4; ++r)
                            wr[(ii * 16 + fq * 4 + r) * 33 + j * 16 + fr] =
                                acc[ii][j][r];
            }
        }
        __syncthreads();
        {
            const float* rd = red + (wave ^ 4) * 1056;
            if (kh == 0) {
#pragma unroll
                for (int ii = 0; ii < 2; ++ii)
#pragma unroll
                    for (int j = 0; j < 2; ++j)
#pragma unroll
                        for (int r = 0; r < 4; ++r)
                            acc[ii][j][r] +=
                                rd[(ii * 16 + fq * 4 + r) * 33 + j * 16 + fr];
            } else {
#pragma unroll
                for (int ii = 0; ii < 2; ++ii)
#pragma unroll
                    for (int j = 0; j < 2; ++j)
#pragma unroll
                        for (int r = 0; r < 4; ++r)
                            acc[2 + ii][j][r] +=
                                rd[(ii * 16 + fq * 4 + r) * 33 + j * 16 + fr];
            }
        }

        // epilogue: + x_t*W_hx + b_h, tanh, bf16 store (kept half only)
#define EPI(I)                                                              \
        {                                                                   \
            const int row0 = bm * 128 + wm + (I) * 16 + fq * 4;             \
            float xv[4];                                                    \
            _Pragma("unroll")                                               \
            for (int r = 0; r < 4; ++r) xv[r] = x[(row0 + r) * T_ + t];     \
            _Pragma("unroll")                                               \
            for (int j = 0; j < 2; ++j) {                                   \
                const int col = bn * 64 + wn + j * 16 + fr;                 \
                _Pragma("unroll")                                           \
                for (int r = 0; r < 4; ++r)                                 \
                    hn[(size_t)(row0 + r) * H_ + col] =                     \
                        (bf16_t)tanhf(acc[I][j][r] + xv[r] * wv[j] + bv[j]);\
            }                                                               \
        }
        if (kh == 0) { EPI(0) EPI(1) } else { EPI(2) EPI(3) }
#undef EPI

        // publish: drain this wave's stores to L2, join waves, bump counter.
        asm volatile("s_waitcnt vmcnt(0)" ::: "memory");
        __syncthreads();
        if (tid == 0)
            __hip_atomic_fetch_add(&g_cnt[t * 8 + bm], 1, __ATOMIC_RELAXED,
                                   __HIP_MEMORY_SCOPE_AGENT);
    }
#undef ITER
#undef CMP
#undef COMPUTE
#undef ISSUE_B
#undef ISSUE_A
}

// p = h_T @ W_ph + b_p : one wave per batch row, fp32 accumulate.
__global__ __launch_bounds__(64) void rnn_proj(const float* __restrict__ Wph,
                                               const float* __restrict__ bp,
                                               float* __restrict__ out, int sb) {
    const int b = blockIdx.x;
    const int l = threadIdx.x;
    const bf16_t* h = g_hb[sb] + (size_t)b * H_;
    float acc[C_];
#pragma unroll
    for (int c = 0; c < C_; ++c) acc[c] = 0.f;
    for (int k = l; k < H_; k += 64) {
        const float hv = (float)h[k];
#pragma unroll
        for (int c = 0; c < C_; ++c)
            acc[c] = fmaf(hv, Wph[k * C_ + c], acc[c]);
    }
#pragma unroll
    for (int off = 32; off > 0; off >>= 1)
#pragma unroll
        for (int c = 0; c < C_; ++c) acc[c] += __shfl_down(acc[c], off);
    if (l == 0) {
#pragma unroll
        for (int c = 0; c < C_; ++c) out[b * C_ + c] = acc[c] + bp[c];
    }
}

extern "C" void kernel_launch(void* const* d_in, const int* in_sizes, int n_in,
                              void* d_out, int out_size, void* d_ws, size_t ws_size,
                              hipStream_t stream) {
    const float* x   = (const float*)d_in[0];   // [1024,128]
    const float* Whx = (const float*)d_in[1];   // [1,2048]
    const float* Whh = (const float*)d_in[2];   // [2048,2048]
    const float* bh  = (const float*)d_in[3];   // [2048]
    const float* Wph = (const float*)d_in[4];   // [2048,10]
    const float* bp  = (const float*)d_in[5];   // [1,10]
    float* out = (float*)d_out;                 // [1024,10]

    static bool attr_set = false;
    if (!attr_set) {
        hipFuncSetAttribute((const void*)rnn_persist,
                            hipFuncAttributeMaxDynamicSharedMemorySize, 147456);
        attr_set = true;
    }

    prep_whhT<<<dim3(64, 64), 256, 0, stream>>>(Whh);
    rnn_init<<<(B_ * H_ / 4) / 256, 256, 0, stream>>>(x, Whx, bh);
    rnn_persist<<<256, 512, 147456, stream>>>(x, Whx, bh);
    rnn_proj<<<B_, 64, 0, stream>>>(Wph, bp, out, (T_ - 1) & 1);
}